// Round 1
// baseline (95.994 us; speedup 1.0000x reference)
//
#include <hip/hip_runtime.h>

#define D_   256
#define R_   128
#define NROW 4096            // B*K
#define TOPK 12
#define ROWS 4               // rows per main block
#define NBLK_MAIN (NROW / ROWS)   // 1024
#define INVSQRT2 0.70710678f

// gelu(x) with u = x/sqrt(2) as input. erf via odd Taylor (deg 15 in u),
// clamped at |u|=1.6 for safety; abs err <= ~5e-5 in range, <=0.03 beyond.
__device__ __forceinline__ float gelu_u(float u) {
    float uc = fminf(fmaxf(u, -1.6f), 1.6f);
    float s  = uc * uc;
    float p  =            -1.4925650e-5f;
    p = fmaf(p, s,         1.2055333e-4f);
    p = fmaf(p, s,        -8.5483270e-4f);
    p = fmaf(p, s,         5.2239776e-3f);
    p = fmaf(p, s,        -2.6866171e-2f);
    p = fmaf(p, s,         1.1283792e-1f);
    p = fmaf(p, s,        -3.7612639e-1f);
    p = fmaf(p, s,         1.1283792f);
    float erfv = uc * p;                 // ~erf(u)
    float v = INVSQRT2 * u;              // 0.5*x
    return fmaf(v, erfv, v);             // 0.5*x*(1+erf(u))
}

// K1: hrb4[(f/4)*R*4 + r*4 + (f%4)] = (receptors[r,:] @ W1[D:, f] + b1[f]) / sqrt(2)
__global__ __launch_bounds__(256) void hrb_kernel(
    const float* __restrict__ receptors, const float* __restrict__ W1,
    const float* __restrict__ b1, float* __restrict__ hrb4)
{
    const int r = blockIdx.x;      // 0..127
    const int f = threadIdx.x;     // 0..255
    const float* wb = W1 + D_ * D_;        // bottom half of W1
    float acc = 0.f;
    #pragma unroll 4
    for (int d = 0; d < D_; d++)
        acc = fmaf(receptors[r * D_ + d], wb[d * D_ + f], acc);
    float val = (acc + b1[f]) * INVSQRT2;
    hrb4[((f >> 2) * R_ + r) * 4 + (f & 3)] = val;
}

// K2: hk[4096,256] = keys[4096,256] @ W1[:256,:256], scaled by 1/sqrt(2)
__global__ __launch_bounds__(256) void hk_gemm(
    const float* __restrict__ keys, const float* __restrict__ W1,
    float* __restrict__ hk)
{
    __shared__ float At[16][64];   // A tile, transposed: At[k][row]
    __shared__ float Bs[16][64];   // B tile: Bs[k][col]
    const int bx = blockIdx.x & 3;        // N tile (4)
    const int by = blockIdx.x >> 2;       // M tile (64)
    const int t  = threadIdx.x;
    const int tx = t & 15, ty = t >> 4;
    const int arow = t >> 2, akq = t & 3;     // A loader: row 0..63, k-quad 0..3
    const int bkr  = t >> 4, bnc = t & 15;    // B loader: k-row 0..15, col-quad
    const float* Aptr = keys + (by * 64 + arow) * D_;
    const int bcol = bx * 64 + bnc * 4;

    float acc[4][4] = {};
    float4 av = *(const float4*)(Aptr + akq * 4);
    float4 bv = *(const float4*)(W1 + bkr * D_ + bcol);
    for (int k0 = 0; k0 < 256; k0 += 16) {
        __syncthreads();
        At[akq * 4 + 0][arow] = av.x;
        At[akq * 4 + 1][arow] = av.y;
        At[akq * 4 + 2][arow] = av.z;
        At[akq * 4 + 3][arow] = av.w;
        *(float4*)&Bs[bkr][bnc * 4] = bv;
        __syncthreads();
        if (k0 + 16 < 256) {   // prefetch next tile (hidden under compute)
            av = *(const float4*)(Aptr + k0 + 16 + akq * 4);
            bv = *(const float4*)(W1 + (k0 + 16 + bkr) * D_ + bcol);
        }
        #pragma unroll
        for (int kk = 0; kk < 16; kk++) {
            float4 a4 = *(const float4*)&At[kk][ty * 4];
            float4 b4 = *(const float4*)&Bs[kk][tx * 4];
            acc[0][0] = fmaf(a4.x, b4.x, acc[0][0]);
            acc[0][1] = fmaf(a4.x, b4.y, acc[0][1]);
            acc[0][2] = fmaf(a4.x, b4.z, acc[0][2]);
            acc[0][3] = fmaf(a4.x, b4.w, acc[0][3]);
            acc[1][0] = fmaf(a4.y, b4.x, acc[1][0]);
            acc[1][1] = fmaf(a4.y, b4.y, acc[1][1]);
            acc[1][2] = fmaf(a4.y, b4.z, acc[1][2]);
            acc[1][3] = fmaf(a4.y, b4.w, acc[1][3]);
            acc[2][0] = fmaf(a4.z, b4.x, acc[2][0]);
            acc[2][1] = fmaf(a4.z, b4.y, acc[2][1]);
            acc[2][2] = fmaf(a4.z, b4.z, acc[2][2]);
            acc[2][3] = fmaf(a4.z, b4.w, acc[2][3]);
            acc[3][0] = fmaf(a4.w, b4.x, acc[3][0]);
            acc[3][1] = fmaf(a4.w, b4.y, acc[3][1]);
            acc[3][2] = fmaf(a4.w, b4.z, acc[3][2]);
            acc[3][3] = fmaf(a4.w, b4.w, acc[3][3]);
        }
    }
    #pragma unroll
    for (int i = 0; i < 4; i++) {
        float4 o4;
        o4.x = acc[i][0] * INVSQRT2;
        o4.y = acc[i][1] * INVSQRT2;
        o4.z = acc[i][2] * INVSQRT2;
        o4.w = acc[i][3] * INVSQRT2;
        *(float4*)(hk + (by * 64 + ty * 4 + i) * D_ + bx * 64 + tx * 4) = o4;
    }
}

// K3: the fused main kernel. One block = 4 (b,k) rows, 256 threads.
__global__ __launch_bounds__(256) void main_kernel(
    const float* __restrict__ keys, const float* __restrict__ receptors,
    const float* __restrict__ W2,   const float* __restrict__ b2p,
    const float* __restrict__ scalep,
    const float* __restrict__ hkp,  const float* __restrict__ hrb4,
    float* __restrict__ out, float* __restrict__ partials)
{
    __shared__ float hk_lds[ROWS][D_];
    __shared__ float w2_lds[D_];
    __shared__ float aff_lds[ROWS][R_];
    __shared__ float bind_lds[ROWS][R_];
    __shared__ float thr_lds[ROWS];
    __shared__ float redE[ROWS][2];
    __shared__ float redS[ROWS][2];
    __shared__ float redN[ROWS][2];
    __shared__ float redX[ROWS][4];
    __shared__ float redV[2][4];

    const int t    = threadIdx.x;
    const int blk  = blockIdx.x;
    const int rowg = blk * ROWS;

    #pragma unroll
    for (int i = 0; i < ROWS; i++)
        hk_lds[i][t] = hkp[(rowg + i) * D_ + t];
    w2_lds[t] = W2[t];
    __syncthreads();

    const int r    = t & 127;
    const int hf   = t >> 7;       // 0: rows 0,1   1: rows 2,3
    const int w    = t >> 6;       // wave id
    const int lane = t & 63;
    const int half = w & 1;        // which r-half of the row this wave covers
    const int lr0  = 2 * hf, lr1 = 2 * hf + 1;

    // ---- Phase B: affinity via gelu over f (the 22us VALU floor) ----
    float acc0 = 0.f, acc1 = 0.f;
    for (int f = 0; f < D_; f += 4) {
        float4 hv = *(const float4*)(hrb4 + ((f >> 2) * R_ + r) * 4);  // coalesced
        float4 k0 = *(const float4*)&hk_lds[lr0][f];                   // broadcast
        float4 k1 = *(const float4*)&hk_lds[lr1][f];
        float4 wv = *(const float4*)&w2_lds[f];
        acc0 = fmaf(gelu_u(k0.x + hv.x), wv.x, acc0);
        acc1 = fmaf(gelu_u(k1.x + hv.x), wv.x, acc1);
        acc0 = fmaf(gelu_u(k0.y + hv.y), wv.y, acc0);
        acc1 = fmaf(gelu_u(k1.y + hv.y), wv.y, acc1);
        acc0 = fmaf(gelu_u(k0.z + hv.z), wv.z, acc0);
        acc1 = fmaf(gelu_u(k1.z + hv.z), wv.z, acc1);
        acc0 = fmaf(gelu_u(k0.w + hv.w), wv.w, acc0);
        acc1 = fmaf(gelu_u(k1.w + hv.w), wv.w, acc1);
    }
    const float b2 = b2p[0];
    const float a0 = acc0 + b2;
    const float a1 = acc1 + b2;
    aff_lds[lr0][r] = a0;
    aff_lds[lr1][r] = a1;
    __syncthreads();

    // ---- Phase C: row max + rank counts (top-12 threshold, tie-safe) ----
    float mx0 = -1e30f, mx1 = -1e30f;
    int cg0 = 0, ce0 = 0, cg1 = 0, ce1 = 0;
    for (int j = 0; j < R_; j += 4) {
        float4 v0 = *(const float4*)&aff_lds[lr0][j];
        float4 v1 = *(const float4*)&aff_lds[lr1][j];
        mx0 = fmaxf(mx0, fmaxf(fmaxf(v0.x, v0.y), fmaxf(v0.z, v0.w)));
        mx1 = fmaxf(mx1, fmaxf(fmaxf(v1.x, v1.y), fmaxf(v1.z, v1.w)));
        cg0 += (v0.x > a0) + (v0.y > a0) + (v0.z > a0) + (v0.w > a0);
        ce0 += (v0.x == a0) + (v0.y == a0) + (v0.z == a0) + (v0.w == a0);
        cg1 += (v1.x > a1) + (v1.y > a1) + (v1.z > a1) + (v1.w > a1);
        ce1 += (v1.x == a1) + (v1.y == a1) + (v1.z == a1) + (v1.w == a1);
    }
    if (cg0 <= TOPK - 1 && cg0 + ce0 >= TOPK) thr_lds[lr0] = a0;
    if (cg1 <= TOPK - 1 && cg1 + ce1 >= TOPK) thr_lds[lr1] = a1;
    __syncthreads();
    const float thr0 = thr_lds[lr0];
    const float thr1 = thr_lds[lr1];

    // ---- Phase D: softmax * sigmoid mask; binding stats ----
    const float e0 = __expf(a0 - mx0);
    const float e1 = __expf(a1 - mx1);
    float s0 = e0, s1 = e1;
    #pragma unroll
    for (int o = 32; o > 0; o >>= 1) {
        s0 += __shfl_xor(s0, o, 64);
        s1 += __shfl_xor(s1, o, 64);
    }
    if (lane == 0) { redE[lr0][half] = s0; redE[lr1][half] = s1; }
    __syncthreads();
    const float den0 = redE[lr0][0] + redE[lr0][1];
    const float den1 = redE[lr1][0] + redE[lr1][1];
    const float sg0 = 1.0f / (1.0f + __expf(-10.0f * (a0 - thr0)));
    const float sg1 = 1.0f / (1.0f + __expf(-10.0f * (a1 - thr1)));
    const float b0  = e0 / den0 * sg0;
    const float b1v = e1 / den1 * sg1;
    bind_lds[lr0][r] = b0;
    bind_lds[lr1][r] = b1v;
    float q0 = b0 * b0,  q1 = b1v * b1v;
    float n0 = b0 * __logf(b0 + 1e-8f);
    float n1 = b1v * __logf(b1v + 1e-8f);
    #pragma unroll
    for (int o = 32; o > 0; o >>= 1) {
        q0 += __shfl_xor(q0, o, 64);
        q1 += __shfl_xor(q1, o, 64);
        n0 += __shfl_xor(n0, o, 64);
        n1 += __shfl_xor(n1, o, 64);
    }
    if (lane == 0) {
        redS[lr0][half] = q0; redS[lr1][half] = q1;
        redN[lr0][half] = n0; redN[lr1][half] = n1;
    }
    __syncthreads();   // bind_lds + redS/redN ready

    if (t == 0) {
        float sb = 0.f, se = 0.f;
        #pragma unroll
        for (int i = 0; i < ROWS; i++) {
            sb += redS[i][0] + redS[i][1];
            se += redN[i][0] + redN[i][1];
        }
        partials[blk * 4 + 0] = sb;
        partials[blk * 4 + 1] = se;
    }

    // ---- Phase F: bound = binding @ receptors; RMS-norm; var partials ----
    // Remap: thread t owns dimension d = t for all 4 rows.
    float bnd0 = 0.f, bnd1 = 0.f, bnd2 = 0.f, bnd3 = 0.f;
    for (int rr = 0; rr < R_; rr += 4) {
        float rc0 = receptors[(rr + 0) * D_ + t];
        float rc1 = receptors[(rr + 1) * D_ + t];
        float rc2 = receptors[(rr + 2) * D_ + t];
        float rc3 = receptors[(rr + 3) * D_ + t];
        float4 v0 = *(const float4*)&bind_lds[0][rr];
        float4 v1 = *(const float4*)&bind_lds[1][rr];
        float4 v2 = *(const float4*)&bind_lds[2][rr];
        float4 v3 = *(const float4*)&bind_lds[3][rr];
        bnd0 = fmaf(rc0, v0.x, fmaf(rc1, v0.y, fmaf(rc2, v0.z, fmaf(rc3, v0.w, bnd0))));
        bnd1 = fmaf(rc0, v1.x, fmaf(rc1, v1.y, fmaf(rc2, v1.z, fmaf(rc3, v1.w, bnd1))));
        bnd2 = fmaf(rc0, v2.x, fmaf(rc1, v2.y, fmaf(rc2, v2.z, fmaf(rc3, v2.w, bnd2))));
        bnd3 = fmaf(rc0, v3.x, fmaf(rc1, v3.y, fmaf(rc2, v3.z, fmaf(rc3, v3.w, bnd3))));
    }
    float x0 = keys[(rowg + 0) * D_ + t] + bnd0;
    float x1 = keys[(rowg + 1) * D_ + t] + bnd1;
    float x2 = keys[(rowg + 2) * D_ + t] + bnd2;
    float x3 = keys[(rowg + 3) * D_ + t] + bnd3;
    float xs0 = x0 * x0, xs1 = x1 * x1, xs2 = x2 * x2, xs3 = x3 * x3;
    #pragma unroll
    for (int o = 32; o > 0; o >>= 1) {
        xs0 += __shfl_xor(xs0, o, 64);
        xs1 += __shfl_xor(xs1, o, 64);
        xs2 += __shfl_xor(xs2, o, 64);
        xs3 += __shfl_xor(xs3, o, 64);
    }
    if (lane == 0) { redX[0][w] = xs0; redX[1][w] = xs1; redX[2][w] = xs2; redX[3][w] = xs3; }
    __syncthreads();
    const float scl = scalep[0];
    float vs = 0.f, vq = 0.f;
    {
        float ms = (redX[0][0] + redX[0][1] + redX[0][2] + redX[0][3]) * (1.0f / D_);
        float rs = scl * rsqrtf(ms + 1e-8f);
        float st = x0 * rs;
        out[(rowg + 0) * D_ + t] = st;
        vs += st; vq += st * st;
    }
    {
        float ms = (redX[1][0] + redX[1][1] + redX[1][2] + redX[1][3]) * (1.0f / D_);
        float rs = scl * rsqrtf(ms + 1e-8f);
        float st = x1 * rs;
        out[(rowg + 1) * D_ + t] = st;
        vs += st; vq += st * st;
    }
    {
        float ms = (redX[2][0] + redX[2][1] + redX[2][2] + redX[2][3]) * (1.0f / D_);
        float rs = scl * rsqrtf(ms + 1e-8f);
        float st = x2 * rs;
        out[(rowg + 2) * D_ + t] = st;
        vs += st; vq += st * st;
    }
    {
        float ms = (redX[3][0] + redX[3][1] + redX[3][2] + redX[3][3]) * (1.0f / D_);
        float rs = scl * rsqrtf(ms + 1e-8f);
        float st = x3 * rs;
        out[(rowg + 3) * D_ + t] = st;
        vs += st; vq += st * st;
    }
    #pragma unroll
    for (int o = 32; o > 0; o >>= 1) {
        vs += __shfl_xor(vs, o, 64);
        vq += __shfl_xor(vq, o, 64);
    }
    if (lane == 0) { redV[0][w] = vs; redV[1][w] = vq; }
    __syncthreads();
    if (t == 0) {
        partials[blk * 4 + 2] = redV[0][0] + redV[0][1] + redV[0][2] + redV[0][3];
        partials[blk * 4 + 3] = redV[1][0] + redV[1][1] + redV[1][2] + redV[1][3];
    }
}

// K4: deterministic reduction of per-block partials -> 3 scalars
__global__ __launch_bounds__(256) void finalize(
    const float* __restrict__ partials, float* __restrict__ out)
{
    __shared__ float sh[4][4];
    const int t = threadIdx.x;
    float s0 = 0.f, s1 = 0.f, s2 = 0.f, s3 = 0.f;
    for (int k = t; k < NBLK_MAIN; k += 256) {
        s0 += partials[k * 4 + 0];
        s1 += partials[k * 4 + 1];
        s2 += partials[k * 4 + 2];
        s3 += partials[k * 4 + 3];
    }
    #pragma unroll
    for (int o = 32; o > 0; o >>= 1) {
        s0 += __shfl_xor(s0, o, 64);
        s1 += __shfl_xor(s1, o, 64);
        s2 += __shfl_xor(s2, o, 64);
        s3 += __shfl_xor(s3, o, 64);
    }
    const int w = t >> 6, lane = t & 63;
    if (lane == 0) { sh[0][w] = s0; sh[1][w] = s1; sh[2][w] = s2; sh[3][w] = s3; }
    __syncthreads();
    if (t == 0) {
        float S0 = sh[0][0] + sh[0][1] + sh[0][2] + sh[0][3];  // sum b^2
        float S1 = sh[1][0] + sh[1][1] + sh[1][2] + sh[1][3];  // sum b*log(b+eps)
        float S2 = sh[2][0] + sh[2][1] + sh[2][2] + sh[2][3];  // sum st
        float S3 = sh[3][0] + sh[3][1] + sh[3][2] + sh[3][3];  // sum st^2
        const float N = (float)(NROW * D_);
        out[NROW * D_ + 0] = S0 / (float)NROW;
        out[NROW * D_ + 1] = -S1 / (float)NROW;
        out[NROW * D_ + 2] = (S3 - S2 * S2 / N) / (N - 1.0f);
    }
}

extern "C" void kernel_launch(void* const* d_in, const int* in_sizes, int n_in,
                              void* d_out, int out_size, void* d_ws, size_t ws_size,
                              hipStream_t stream) {
    const float* keys      = (const float*)d_in[0];
    const float* receptors = (const float*)d_in[1];
    const float* W1        = (const float*)d_in[2];
    const float* b1        = (const float*)d_in[3];
    const float* W2        = (const float*)d_in[4];
    const float* b2        = (const float*)d_in[5];
    const float* oscale    = (const float*)d_in[6];
    float* out = (float*)d_out;
    float* ws  = (float*)d_ws;

    float* hrb4     = ws;                        // 32768 floats (128 KB)
    float* hkp      = ws + 32768;                // 1048576 floats (4 MB)
    float* partials = ws + 32768 + NROW * D_;    // 4096 floats

    hrb_kernel<<<dim3(R_), dim3(D_), 0, stream>>>(receptors, W1, b1, hrb4);
    hk_gemm<<<dim3(256), dim3(256), 0, stream>>>(keys, W1, hkp);
    main_kernel<<<dim3(NBLK_MAIN), dim3(256), 0, stream>>>(
        keys, receptors, W2, b2, oscale, hkp, hrb4, out, partials);
    finalize<<<dim3(1), dim3(256), 0, stream>>>(partials, out);
}

// Round 3
// 82.333 us; speedup vs baseline: 1.1659x; 1.1659x over previous
//
#include <hip/hip_runtime.h>

#define D_   256
#define R_   128
#define NROW 4096            // B*K
#define TOPK 12
#define ROWS 4               // rows per main block
#define NBLK_MAIN (NROW / ROWS)   // 1024
#define INVSQRT2 0.70710678f

typedef _Float16 h2 __attribute__((ext_vector_type(2)));

__device__ __forceinline__ h2 bch2(unsigned u) { return __builtin_bit_cast(h2, u); }
__device__ __forceinline__ unsigned bcu(h2 h)  { return __builtin_bit_cast(unsigned, h); }
__device__ __forceinline__ h2 h2splat(float x) { _Float16 v = (_Float16)x; h2 r; r.x = v; r.y = v; return r; }
__device__ __forceinline__ h2 h2pack(float a, float b) { h2 r; r.x = (_Float16)a; r.y = (_Float16)b; return r; }

// gelu with u = x/sqrt(2) as input, packed f16x2. erf via deg-13 odd Taylor,
// clamped at |u|=1.45 (|u|max in data ~1.4; f16 noise ~1e-3 dominates anyway).
// Plain operators contract to v_pk_fma_f16 at -O3.
__device__ __forceinline__ h2 gelu2(h2 u) {
    h2 uc = __builtin_elementwise_min(
                __builtin_elementwise_max(u, h2splat(-1.45f)), h2splat(1.45f));
    h2 s  = uc * uc;
    h2 p  = h2splat(1.2055333e-4f);
    p = p * s + h2splat(-8.5483270e-4f);
    p = p * s + h2splat(5.2239776e-3f);
    p = p * s + h2splat(-2.6866171e-2f);
    p = p * s + h2splat(1.1283792e-1f);
    p = p * s + h2splat(-3.7612639e-1f);
    p = p * s + h2splat(1.1283792f);
    h2 erfv = uc * p;
    h2 v    = u * h2splat(INVSQRT2);   // 0.5*x
    return v * erfv + v;
}

// K1: hrbq[f4][r] = packed f16x4 of (receptors[r,:]@W1[D:,4f4..] + b1)/sqrt(2)
__global__ __launch_bounds__(256) void hrb_kernel(
    const float* __restrict__ receptors, const float* __restrict__ W1,
    const float* __restrict__ b1, uint2* __restrict__ hrbq)
{
    __shared__ float tmp[D_];
    const int r = blockIdx.x;      // 0..127
    const int f = threadIdx.x;     // 0..255
    const float* wb = W1 + D_ * D_;
    float acc = 0.f;
    #pragma unroll 4
    for (int d = 0; d < D_; d++)
        acc = fmaf(receptors[r * D_ + d], wb[d * D_ + f], acc);
    tmp[f] = (acc + b1[f]) * INVSQRT2;
    __syncthreads();
    if (f < 64) {
        unsigned lo = bcu(h2pack(tmp[4 * f + 0], tmp[4 * f + 1]));
        unsigned hi = bcu(h2pack(tmp[4 * f + 2], tmp[4 * f + 3]));
        hrbq[f * R_ + r] = make_uint2(lo, hi);
    }
}

// K2: hkq[row][f4] = packed f16x4 of (keys @ W1[:D]) / sqrt(2)
__global__ __launch_bounds__(256) void hk_gemm(
    const float* __restrict__ keys, const float* __restrict__ W1,
    uint2* __restrict__ hkq)
{
    __shared__ float At[16][64];
    __shared__ float Bs[16][64];
    const int bx = blockIdx.x & 3;
    const int by = blockIdx.x >> 2;
    const int t  = threadIdx.x;
    const int tx = t & 15, ty = t >> 4;
    const int arow = t >> 2, akq = t & 3;
    const int bkr  = t >> 4, bnc = t & 15;
    const float* Aptr = keys + (by * 64 + arow) * D_;
    const int bcol = bx * 64 + bnc * 4;

    float acc[4][4] = {};
    float4 av = *(const float4*)(Aptr + akq * 4);
    float4 bv = *(const float4*)(W1 + bkr * D_ + bcol);
    for (int k0 = 0; k0 < 256; k0 += 16) {
        __syncthreads();
        At[akq * 4 + 0][arow] = av.x;
        At[akq * 4 + 1][arow] = av.y;
        At[akq * 4 + 2][arow] = av.z;
        At[akq * 4 + 3][arow] = av.w;
        *(float4*)&Bs[bkr][bnc * 4] = bv;
        __syncthreads();
        if (k0 + 16 < 256) {
            av = *(const float4*)(Aptr + k0 + 16 + akq * 4);
            bv = *(const float4*)(W1 + (k0 + 16 + bkr) * D_ + bcol);
        }
        #pragma unroll
        for (int kk = 0; kk < 16; kk++) {
            float4 a4 = *(const float4*)&At[kk][ty * 4];
            float4 b4 = *(const float4*)&Bs[kk][tx * 4];
            acc[0][0] = fmaf(a4.x, b4.x, acc[0][0]);
            acc[0][1] = fmaf(a4.x, b4.y, acc[0][1]);
            acc[0][2] = fmaf(a4.x, b4.z, acc[0][2]);
            acc[0][3] = fmaf(a4.x, b4.w, acc[0][3]);
            acc[1][0] = fmaf(a4.y, b4.x, acc[1][0]);
            acc[1][1] = fmaf(a4.y, b4.y, acc[1][1]);
            acc[1][2] = fmaf(a4.y, b4.z, acc[1][2]);
            acc[1][3] = fmaf(a4.y, b4.w, acc[1][3]);
            acc[2][0] = fmaf(a4.z, b4.x, acc[2][0]);
            acc[2][1] = fmaf(a4.z, b4.y, acc[2][1]);
            acc[2][2] = fmaf(a4.z, b4.z, acc[2][2]);
            acc[2][3] = fmaf(a4.z, b4.w, acc[2][3]);
            acc[3][0] = fmaf(a4.w, b4.x, acc[3][0]);
            acc[3][1] = fmaf(a4.w, b4.y, acc[3][1]);
            acc[3][2] = fmaf(a4.w, b4.z, acc[3][2]);
            acc[3][3] = fmaf(a4.w, b4.w, acc[3][3]);
        }
    }
    #pragma unroll
    for (int i = 0; i < 4; i++) {
        unsigned lo = bcu(h2pack(acc[i][0] * INVSQRT2, acc[i][1] * INVSQRT2));
        unsigned hi = bcu(h2pack(acc[i][2] * INVSQRT2, acc[i][3] * INVSQRT2));
        hkq[(by * 64 + ty * 4 + i) * 64 + bx * 16 + tx] = make_uint2(lo, hi);
    }
}

// K3: fused main kernel. One block = 4 rows, 512 threads (8 waves).
__global__ __launch_bounds__(512, 8) void main_kernel(
    const float* __restrict__ keys, const float* __restrict__ receptors,
    const float* __restrict__ W2,   const float* __restrict__ b2p,
    const float* __restrict__ scalep,
    const uint2* __restrict__ hkq,  const uint2* __restrict__ hrbq,
    float* __restrict__ out, float* __restrict__ partials)
{
    __shared__ uint2 hkl[ROWS][64];          // 2 KB
    __shared__ uint2 w2l[64];                // 0.5 KB
    __shared__ float part_lds[ROWS][2][R_];  // 4 KB
    __shared__ float aff_lds[ROWS][R_];      // 2 KB
    __shared__ float bind_lds[ROWS][R_];     // 2 KB
    __shared__ float thr_lds[ROWS];
    __shared__ float redE[ROWS][2];
    __shared__ float redS[ROWS][2];
    __shared__ float redN[ROWS][2];
    __shared__ float redX[ROWS][8];
    __shared__ float redV[2][8];

    const int t    = threadIdx.x;
    const int blk  = blockIdx.x;
    const int rowg = blk * ROWS;

    if (t < ROWS * 64) {
        hkl[t >> 6][t & 63] = hkq[rowg * 64 + t];
    } else if (t < ROWS * 64 + 64) {
        int f = t - ROWS * 64;
        unsigned lo = bcu(h2pack(W2[4 * f + 0], W2[4 * f + 1]));
        unsigned hi = bcu(h2pack(W2[4 * f + 2], W2[4 * f + 3]));
        w2l[f] = make_uint2(lo, hi);
    }
    __syncthreads();

    const int r    = t & 127;
    const int part = t >> 7;          // 0..3
    const int rp   = part >> 1;       // row pair: rows 2rp, 2rp+1
    const int fh   = part & 1;        // f half
    const int f4b  = fh * 32;

    // ---- Phase B: affinity partials via packed-f16 gelu ----
    h2 acc00 = h2splat(0.f), acc01 = acc00, acc10 = acc00, acc11 = acc00;
    #pragma unroll 4
    for (int f4 = f4b; f4 < f4b + 32; ++f4) {
        uint2 hq = hrbq[f4 * R_ + r];           // coalesced 8B, L2-hot
        h2 hr01 = bch2(hq.x), hr23 = bch2(hq.y);
        uint2 ka = hkl[2 * rp + 0][f4];         // LDS broadcast
        uint2 kb = hkl[2 * rp + 1][f4];
        uint2 wq = w2l[f4];
        h2 w01 = bch2(wq.x), w23 = bch2(wq.y);
        acc00 = gelu2(bch2(ka.x) + hr01) * w01 + acc00;
        acc01 = gelu2(bch2(ka.y) + hr23) * w23 + acc01;
        acc10 = gelu2(bch2(kb.x) + hr01) * w01 + acc10;
        acc11 = gelu2(bch2(kb.y) + hr23) * w23 + acc11;
    }
    part_lds[2 * rp + 0][fh][r] = (float)acc00.x + (float)acc00.y
                                + (float)acc01.x + (float)acc01.y;
    part_lds[2 * rp + 1][fh][r] = (float)acc10.x + (float)acc10.y
                                + (float)acc11.x + (float)acc11.y;
    __syncthreads();

    // ---- Phase C: combine halves; row max + rank counts (top-12, tie-safe) ----
    const int row = t >> 7;
    const float b2 = b2p[0];
    const float a  = part_lds[row][0][r] + part_lds[row][1][r] + b2;
    aff_lds[row][r] = a;
    __syncthreads();

    float mx = -1e30f;
    int cg = 0, ce = 0;
    for (int j = 0; j < R_; j += 4) {
        float4 v = *(const float4*)&aff_lds[row][j];
        mx = fmaxf(mx, fmaxf(fmaxf(v.x, v.y), fmaxf(v.z, v.w)));
        cg += (v.x > a) + (v.y > a) + (v.z > a) + (v.w > a);
        ce += (v.x == a) + (v.y == a) + (v.z == a) + (v.w == a);
    }
    if (cg <= TOPK - 1 && cg + ce >= TOPK) thr_lds[row] = a;
    __syncthreads();
    const float thr = thr_lds[row];

    // ---- Phase D: softmax * sigmoid mask; binding stats ----
    const int w    = t >> 6;          // wave 0..7
    const int lane = t & 63;
    const int half = w & 1;
    const float e = __expf(a - mx);
    float s = e;
    #pragma unroll
    for (int o = 32; o > 0; o >>= 1) s += __shfl_xor(s, o, 64);
    if (lane == 0) redE[row][half] = s;
    __syncthreads();
    const float den = redE[row][0] + redE[row][1];
    const float sg  = 1.0f / (1.0f + __expf(-10.0f * (a - thr)));
    const float bv  = e / den * sg;
    bind_lds[row][r] = bv;
    float q = bv * bv;
    float n = bv * __logf(bv + 1e-8f);
    #pragma unroll
    for (int o = 32; o > 0; o >>= 1) {
        q += __shfl_xor(q, o, 64);
        n += __shfl_xor(n, o, 64);
    }
    if (lane == 0) { redS[row][half] = q; redN[row][half] = n; }
    __syncthreads();

    if (t == 0) {
        float sb = 0.f, se = 0.f;
        #pragma unroll
        for (int i = 0; i < ROWS; i++) {
            sb += redS[i][0] + redS[i][1];
            se += redN[i][0] + redN[i][1];
        }
        partials[blk * 4 + 0] = sb;
        partials[blk * 4 + 1] = se;
    }

    // ---- Phase F: bound = binding @ receptors; RMS-norm; var partials ----
    const int d  = t & 255;
    const int rh = t >> 8;            // 0,1 -> rows 2rh, 2rh+1
    const int R0 = 2 * rh, R1 = 2 * rh + 1;
    float bnd0 = 0.f, bnd1 = 0.f;
    for (int rr = 0; rr < R_; rr += 4) {
        float rc0 = receptors[(rr + 0) * D_ + d];
        float rc1 = receptors[(rr + 1) * D_ + d];
        float rc2 = receptors[(rr + 2) * D_ + d];
        float rc3 = receptors[(rr + 3) * D_ + d];
        float4 v0 = *(const float4*)&bind_lds[R0][rr];
        float4 v1 = *(const float4*)&bind_lds[R1][rr];
        bnd0 = fmaf(rc0, v0.x, fmaf(rc1, v0.y, fmaf(rc2, v0.z, fmaf(rc3, v0.w, bnd0))));
        bnd1 = fmaf(rc0, v1.x, fmaf(rc1, v1.y, fmaf(rc2, v1.z, fmaf(rc3, v1.w, bnd1))));
    }
    float x0 = keys[(rowg + R0) * D_ + d] + bnd0;
    float x1 = keys[(rowg + R1) * D_ + d] + bnd1;
    float xs0 = x0 * x0, xs1 = x1 * x1;
    #pragma unroll
    for (int o = 32; o > 0; o >>= 1) {
        xs0 += __shfl_xor(xs0, o, 64);
        xs1 += __shfl_xor(xs1, o, 64);
    }
    if (lane == 0) { redX[R0][w] = xs0; redX[R1][w] = xs1; }
    __syncthreads();
    const float scl = scalep[0];
    const int wb = rh * 4;
    float vs = 0.f, vq = 0.f;
    {
        float ms = (redX[R0][wb] + redX[R0][wb + 1] + redX[R0][wb + 2] + redX[R0][wb + 3]) * (1.0f / D_);
        float rs = scl * rsqrtf(ms + 1e-8f);
        float st = x0 * rs;
        out[(rowg + R0) * D_ + d] = st;
        vs += st; vq += st * st;
    }
    {
        float ms = (redX[R1][wb] + redX[R1][wb + 1] + redX[R1][wb + 2] + redX[R1][wb + 3]) * (1.0f / D_);
        float rs = scl * rsqrtf(ms + 1e-8f);
        float st = x1 * rs;
        out[(rowg + R1) * D_ + d] = st;
        vs += st; vq += st * st;
    }
    #pragma unroll
    for (int o = 32; o > 0; o >>= 1) {
        vs += __shfl_xor(vs, o, 64);
        vq += __shfl_xor(vq, o, 64);
    }
    if (lane == 0) { redV[0][w] = vs; redV[1][w] = vq; }
    __syncthreads();
    if (t == 0) {
        float v2s = 0.f, v2q = 0.f;
        #pragma unroll
        for (int i = 0; i < 8; i++) { v2s += redV[0][i]; v2q += redV[1][i]; }
        partials[blk * 4 + 2] = v2s;
        partials[blk * 4 + 3] = v2q;
    }
}

// K4: deterministic reduction of per-block partials -> 3 scalars
__global__ __launch_bounds__(256) void finalize(
    const float* __restrict__ partials, float* __restrict__ out)
{
    __shared__ float sh[4][4];
    const int t = threadIdx.x;
    float s0 = 0.f, s1 = 0.f, s2 = 0.f, s3 = 0.f;
    for (int k = t; k < NBLK_MAIN; k += 256) {
        s0 += partials[k * 4 + 0];
        s1 += partials[k * 4 + 1];
        s2 += partials[k * 4 + 2];
        s3 += partials[k * 4 + 3];
    }
    #pragma unroll
    for (int o = 32; o > 0; o >>= 1) {
        s0 += __shfl_xor(s0, o, 64);
        s1 += __shfl_xor(s1, o, 64);
        s2 += __shfl_xor(s2, o, 64);
        s3 += __shfl_xor(s3, o, 64);
    }
    const int w = t >> 6, lane = t & 63;
    if (lane == 0) { sh[0][w] = s0; sh[1][w] = s1; sh[2][w] = s2; sh[3][w] = s3; }
    __syncthreads();
    if (t == 0) {
        float S0 = sh[0][0] + sh[0][1] + sh[0][2] + sh[0][3];
        float S1 = sh[1][0] + sh[1][1] + sh[1][2] + sh[1][3];
        float S2 = sh[2][0] + sh[2][1] + sh[2][2] + sh[2][3];
        float S3 = sh[3][0] + sh[3][1] + sh[3][2] + sh[3][3];
        const float N = (float)(NROW * D_);
        out[NROW * D_ + 0] = S0 / (float)NROW;
        out[NROW * D_ + 1] = -S1 / (float)NROW;
        out[NROW * D_ + 2] = (S3 - S2 * S2 / N) / (N - 1.0f);
    }
}

extern "C" void kernel_launch(void* const* d_in, const int* in_sizes, int n_in,
                              void* d_out, int out_size, void* d_ws, size_t ws_size,
                              hipStream_t stream) {
    const float* keys      = (const float*)d_in[0];
    const float* receptors = (const float*)d_in[1];
    const float* W1        = (const float*)d_in[2];
    const float* b1        = (const float*)d_in[3];
    const float* W2        = (const float*)d_in[4];
    const float* b2        = (const float*)d_in[5];
    const float* oscale    = (const float*)d_in[6];
    float* out = (float*)d_out;
    char* ws   = (char*)d_ws;

    uint2* hrbq     = (uint2*)ws;                      // 64*128*8B = 64 KB
    uint2* hkq      = (uint2*)(ws + 65536);            // 4096*64*8B = 2 MB
    float* partials = (float*)(ws + 65536 + 2097152);  // 4096 floats

    hrb_kernel<<<dim3(R_), dim3(D_), 0, stream>>>(receptors, W1, b1, hrbq);
    hk_gemm<<<dim3(256), dim3(256), 0, stream>>>(keys, W1, hkq);
    main_kernel<<<dim3(NBLK_MAIN), dim3(512), 0, stream>>>(
        keys, receptors, W2, b2, oscale, hkq, hrbq, out, partials);
    finalize<<<dim3(1), dim3(256), 0, stream>>>(partials, out);
}